// Round 2
// baseline (378.688 us; speedup 1.0000x reference)
//
#include <hip/hip_runtime.h>
#include <hip/hip_fp16.h>

#define M_DIM 16384
#define K_DIM 2048
#define N_DIM 2048

#define BM 256
#define BN 256
#define BK 64
#define NT (K_DIM / BK)

typedef int int4v  __attribute__((ext_vector_type(4)));
typedef int int16v __attribute__((ext_vector_type(16)));

__device__ __forceinline__ void gl_lds16(const void* g, void* l) {
    __builtin_amdgcn_global_load_lds(
        (const __attribute__((address_space(1))) void*)g,
        (__attribute__((address_space(3))) void*)l,
        16, 0, 0);
}

__device__ __forceinline__ int pack4(int4v v) {
    return (v[0] & 255) | ((v[1] & 255) << 8) | ((v[2] & 255) << 16) | (v[3] << 24);
}

// x: int32 [M,K] -> int8 [M,K]; lane-contiguous loads/stores
__global__ void pack_x_kernel(const int* __restrict__ x, char* __restrict__ xp) {
    const int4v* src = (const int4v*)x;
    int* dst = (int*)xp;
    int base = blockIdx.x * 1024 + threadIdx.x;
#pragma unroll
    for (int j = 0; j < 4; ++j) {
        int i = base + j * 256;
        dst[i] = pack4(src[i]);
    }
}

// weight: int32 [K,N] -> int8 WT [N,K] (transpose + pack), 64x64 tiles via LDS
__global__ void wt_pack_kernel(const int* __restrict__ w, char* __restrict__ wt) {
    __shared__ char tile[64][68];
    int b  = blockIdx.x;
    int k0 = (b & 31) * 64;
    int n0 = (b >> 5) * 64;
    int t  = threadIdx.x;
    int r  = t >> 2;
    int c  = (t & 3) * 16;

    const int* src = w + (size_t)(k0 + r) * N_DIM + n0 + c;
    int4v a = *(const int4v*)(src + 0);
    int4v bb = *(const int4v*)(src + 4);
    int4v cc = *(const int4v*)(src + 8);
    int4v dd = *(const int4v*)(src + 12);
    *(int*)&tile[r][c + 0]  = pack4(a);
    *(int*)&tile[r][c + 4]  = pack4(bb);
    *(int*)&tile[r][c + 8]  = pack4(cc);
    *(int*)&tile[r][c + 12] = pack4(dd);
    __syncthreads();

    char buf[16];
#pragma unroll
    for (int j = 0; j < 16; ++j) buf[j] = tile[c + j][r];
    *(int4v*)(wt + (size_t)(n0 + r) * K_DIM + k0 + c) = *(int4v*)buf;
}

// GEMM: A int8 [M,K], BT int8 [N,K] -> C fp32 [M,N] (+bias)
// 256x256 tile, BK=64, 256 thr = 4 waves (2x2), wave tile 128x128 = acc[4][4]
// of 32x32x32 i8 MFMA (16 MFMA per 8 frag reads = 512 B LDS/inst -> LDS read
// demand ~64 B/cyc at full i8 rate, under the 85-112 B/cyc LDS ceiling).
// 1 wave/SIMD; overlap is pure ILP: 32 independent MFMAs (~1165 cyc/CU) per
// K-tile cover the staging latency (gl_lds issued at tile start, single
// counted vmcnt(0) drain at tile end) and the ds_read bursts (compiler lgkm).
// One barrier per K-tile. Double-buffered LDS 64 KiB.
// LDS layout (16B slots, 4 chunks/row): slot = r*4 + (cg ^ (r&3)); staging is
// slot-linear (gl_lds wave-uniform dest) with pre-swizzled global source;
// fragment reads spread across all bank groups (balanced = b128 BW floor).
__global__ __launch_bounds__(256, 1)
void gemm_i8_kernel(const char* __restrict__ A, const char* __restrict__ BT,
                    const __half* __restrict__ bias, float* __restrict__ C) {
    __shared__ char Asm[2][BM * BK];   // 2 x 16384 B
    __shared__ char Bsm[2][BN * BK];   // 2 x 16384 B

    const int bid = blockIdx.x;
    const int nt = bid & 7;             // n fastest: 8 consecutive blocks share an A panel (L3)
    const int mt = bid >> 3;
    const int R0 = mt * BM, C0 = nt * BN;

    const int t = threadIdx.x;
    const int lane = t & 63;
    const int w = t >> 6;
    const int wm = w >> 1;              // 0..1 row-half
    const int wn = w & 1;               // 0..1 col-half
    const int l31 = lane & 31, khl = lane >> 5;

    int16v acc[4][4];
#pragma unroll
    for (int i = 0; i < 4; ++i)
#pragma unroll
        for (int j = 0; j < 4; ++j) acc[i][j] = (int16v)0;

    // staging: thread owns slots t + 256*j (j=0..3); slot s -> row s>>2,
    // stored chunk s&3, global chunk cg = (s&3)^(row&3)
    unsigned aoff[4], boff[4];
    int ldst[4];
#pragma unroll
    for (int j = 0; j < 4; ++j) {
        int s = t + j * 256;
        int r = s >> 2;
        int cg = (s & 3) ^ (r & 3);
        aoff[j] = (unsigned)(R0 + r) * K_DIM + cg * 16;
        boff[j] = (unsigned)(C0 + r) * K_DIM + cg * 16;
        ldst[j] = s * 16;
    }

    // fragment row-slot bases (row*4); row&3 == l31&3 (bases are mult. of 32)
    int arow4[4], brow4[4];
#pragma unroll
    for (int i = 0; i < 4; ++i) arow4[i] = (wm * 128 + i * 32 + l31) * 4;
#pragma unroll
    for (int j = 0; j < 4; ++j) brow4[j] = (wn * 128 + j * 32 + l31) * 4;
    const int sw0 = (khl)     ^ (l31 & 3);   // ks=0: logical chunk khl
    const int sw1 = (2 + khl) ^ (l31 & 3);   // ks=1: logical chunk 2+khl

    // prologue: stage tile 0 -> buffer 0, full drain
#pragma unroll
    for (int j = 0; j < 4; ++j) gl_lds16(A + aoff[j], &Asm[0][ldst[j]]);
#pragma unroll
    for (int j = 0; j < 4; ++j) gl_lds16(BT + boff[j], &Bsm[0][ldst[j]]);
    asm volatile("s_waitcnt vmcnt(0)" ::: "memory");
    __builtin_amdgcn_s_barrier();

#define TILE(cur, kt)                                                           \
    {                                                                           \
        if ((kt) + 1 < NT) {                                                    \
            const int knext = ((kt) + 1) * BK;                                  \
            _Pragma("unroll")                                                   \
            for (int j = 0; j < 4; ++j)                                         \
                gl_lds16(A + aoff[j] + knext, &Asm[(cur) ^ 1][ldst[j]]);        \
            _Pragma("unroll")                                                   \
            for (int j = 0; j < 4; ++j)                                         \
                gl_lds16(BT + boff[j] + knext, &Bsm[(cur) ^ 1][ldst[j]]);       \
        }                                                                       \
        int4v a0[4], b0[4], a1[4], b1[4];                                       \
        _Pragma("unroll")                                                       \
        for (int i = 0; i < 4; ++i)                                             \
            a0[i] = *(const int4v*)&Asm[cur][(arow4[i] + sw0) * 16];            \
        _Pragma("unroll")                                                       \
        for (int j = 0; j < 4; ++j)                                             \
            b0[j] = *(const int4v*)&Bsm[cur][(brow4[j] + sw0) * 16];            \
        _Pragma("unroll")                                                       \
        for (int i = 0; i < 4; ++i)                                             \
            a1[i] = *(const int4v*)&Asm[cur][(arow4[i] + sw1) * 16];            \
        _Pragma("unroll")                                                       \
        for (int j = 0; j < 4; ++j)                                             \
            b1[j] = *(const int4v*)&Bsm[cur][(brow4[j] + sw1) * 16];            \
        _Pragma("unroll")                                                       \
        for (int i = 0; i < 4; ++i) {                                           \
            _Pragma("unroll")                                                   \
            for (int j = 0; j < 4; ++j)                                         \
                acc[i][j] = __builtin_amdgcn_mfma_i32_32x32x32_i8(              \
                    a0[i], b0[j], acc[i][j], 0, 0, 0);                          \
        }                                                                       \
        _Pragma("unroll")                                                       \
        for (int i = 0; i < 4; ++i) {                                           \
            _Pragma("unroll")                                                   \
            for (int j = 0; j < 4; ++j)                                         \
                acc[i][j] = __builtin_amdgcn_mfma_i32_32x32x32_i8(              \
                    a1[i], b1[j], acc[i][j], 0, 0, 0);                          \
        }                                                                       \
        asm volatile("s_waitcnt vmcnt(0)" ::: "memory");                        \
        __builtin_amdgcn_s_barrier();                                           \
    }

    for (int kt = 0; kt < NT; kt += 2) {
        TILE(0, kt)
        TILE(1, kt + 1)
    }
#undef TILE

    // epilogue: C/D layout col=lane&31, row=(reg&3)+8*(reg>>2)+4*(lane>>5)
    const int col = l31;
    const int rb = khl * 4;
#pragma unroll
    for (int j = 0; j < 4; ++j) {
        const int cn = C0 + wn * 128 + j * 32 + col;
        const float bv = __half2float(bias[cn]);
#pragma unroll
        for (int i = 0; i < 4; ++i) {
            const int rm = R0 + wm * 128 + i * 32 + rb;
#pragma unroll
            for (int reg = 0; reg < 16; ++reg) {
                const int row = rm + (reg & 3) + 8 * (reg >> 2);
                C[(size_t)row * N_DIM + cn] = (float)acc[i][j][reg] + bv;
            }
        }
    }
}

extern "C" void kernel_launch(void* const* d_in, const int* in_sizes, int n_in,
                              void* d_out, int out_size, void* d_ws, size_t ws_size,
                              hipStream_t stream) {
    const int* x = (const int*)d_in[0];
    const int* wgt = (const int*)d_in[1];
    const __half* bias = (const __half*)d_in[2];
    float* out = (float*)d_out;

    char* xp = (char*)d_ws;                                   // 32 MiB packed A
    char* wt = (char*)d_ws + (size_t)M_DIM * K_DIM;           // 4 MiB packed W^T

    pack_x_kernel<<<(M_DIM * (size_t)K_DIM) / 4 / 1024, 256, 0, stream>>>(x, xp);
    wt_pack_kernel<<<(K_DIM / 64) * (N_DIM / 64), 256, 0, stream>>>(wgt, wt);
    gemm_i8_kernel<<<(M_DIM / BM) * (N_DIM / BN), 256, 0, stream>>>(xp, wt, bias, out);
}

// Round 3
// 314.427 us; speedup vs baseline: 1.2044x; 1.2044x over previous
//
#include <hip/hip_runtime.h>
#include <hip/hip_fp16.h>

#define M_DIM 16384
#define K_DIM 2048
#define N_DIM 2048

#define BM 256
#define BN 256
#define BK 128
#define NT (K_DIM / BK)

typedef int int4v  __attribute__((ext_vector_type(4)));
typedef int int16v __attribute__((ext_vector_type(16)));

__device__ __forceinline__ void gl_lds16(const void* g, void* l) {
    __builtin_amdgcn_global_load_lds(
        (const __attribute__((address_space(1))) void*)g,
        (__attribute__((address_space(3))) void*)l,
        16, 0, 0);
}

__device__ __forceinline__ int pack4(int4v v) {
    return (v[0] & 255) | ((v[1] & 255) << 8) | ((v[2] & 255) << 16) | (v[3] << 24);
}

// x: int32 [M,K] -> int8 [M,K]; lane-contiguous loads/stores
__global__ void pack_x_kernel(const int* __restrict__ x, char* __restrict__ xp) {
    const int4v* src = (const int4v*)x;
    int* dst = (int*)xp;
    int base = blockIdx.x * 1024 + threadIdx.x;
#pragma unroll
    for (int j = 0; j < 4; ++j) {
        int i = base + j * 256;
        dst[i] = pack4(src[i]);
    }
}

// weight: int32 [K,N] -> int8 WT [N,K] (transpose + pack), 64x64 tiles via LDS
__global__ void wt_pack_kernel(const int* __restrict__ w, char* __restrict__ wt) {
    __shared__ char tile[64][68];
    int b  = blockIdx.x;
    int k0 = (b & 31) * 64;
    int n0 = (b >> 5) * 64;
    int t  = threadIdx.x;
    int r  = t >> 2;
    int c  = (t & 3) * 16;

    const int* src = w + (size_t)(k0 + r) * N_DIM + n0 + c;
    int4v a = *(const int4v*)(src + 0);
    int4v bb = *(const int4v*)(src + 4);
    int4v cc = *(const int4v*)(src + 8);
    int4v dd = *(const int4v*)(src + 12);
    *(int*)&tile[r][c + 0]  = pack4(a);
    *(int*)&tile[r][c + 4]  = pack4(bb);
    *(int*)&tile[r][c + 8]  = pack4(cc);
    *(int*)&tile[r][c + 12] = pack4(dd);
    __syncthreads();

    char buf[16];
#pragma unroll
    for (int j = 0; j < 16; ++j) buf[j] = tile[c + j][r];
    *(int4v*)(wt + (size_t)(n0 + r) * K_DIM + k0 + c) = *(int4v*)buf;
}

// GEMM: A int8 [M,K], BT int8 [N,K] -> C fp32 [M,N] (+bias)
// 256x256 tile, BK=128, 512 thr = 8 waves (2M x 4N), wave tile 128x64 =
// acc[4][2] (128 regs -> 2 waves/SIMD at the 256-VGPR cap). Double-buffered
// LDS 128 KiB, 1 block/CU. R0-style schedule (the proven one): per K-tile,
//   {8 gl_lds prefetch of tile t+1 -> buf^1}  then
//   for ks=0..3 { 6 ds_read_b128 frags; 8 MFMA }   (compiler pipelines lgkm)
//   vmcnt(0) drain (covered by ~2300 cyc compute span); ONE barrier.
// vs R1: same geometry, 8x fewer barriers -> LDS/MFMA phases overlap across
// waves instead of adding. vs R0: 0.75 KB LDS-read per MFMA instead of 1.0,
// and 2x the MFMA work per staged byte.
// LDS layout (16B slots, 8 chunks/row, XOR-swizzled): slot = r*8 + (cg^(r&7)).
// Staging slot-linear (gl_lds wave-uniform dest) with pre-swizzled global
// source; fragment reads give distinct slot%8 per 8-lane group -> conflict-free.
__global__ __launch_bounds__(512, 2)
void gemm_i8_kernel(const char* __restrict__ A, const char* __restrict__ BT,
                    const __half* __restrict__ bias, float* __restrict__ C) {
    __shared__ char Asm[2][BM * BK];   // 2 x 32768 B
    __shared__ char Bsm[2][BN * BK];   // 2 x 32768 B

    const int bid = blockIdx.x;
    const int mt = bid & 63;            // m fastest: B panel (512 KB) stays hot in L2
    const int nt = bid >> 6;
    const int R0 = mt * BM, C0 = nt * BN;

    const int t = threadIdx.x;
    const int lane = t & 63;
    const int w = t >> 6;
    const int wm = w >> 2;              // 0..1 row-half (128 rows)
    const int wn = w & 3;               // 0..3 col-quarter (64 cols)
    const int l31 = lane & 31, l7 = lane & 7, khl = lane >> 5;

    int16v acc[4][2];
#pragma unroll
    for (int i = 0; i < 4; ++i)
#pragma unroll
        for (int j = 0; j < 2; ++j) acc[i][j] = (int16v)0;

    // staging: thread owns slots t + 512*j; slot s -> row s>>3, stored chunk s&7,
    // global chunk cg = (s&7)^(row&7)
    unsigned aoff[4], boff[4];
    int ldst[4];
#pragma unroll
    for (int j = 0; j < 4; ++j) {
        int s = t + j * 512;
        int r = s >> 3;
        int cg = (s & 7) ^ (r & 7);
        aoff[j] = (unsigned)(R0 + r) * K_DIM + cg * 16;
        boff[j] = (unsigned)(C0 + r) * K_DIM + cg * 16;
        ldst[j] = s * 16;
    }

    // fragment row-slot bases (row*8); row&7 == l7 (bases are mult. of 32)
    int arows[4], brows[2];
#pragma unroll
    for (int i = 0; i < 4; ++i) arows[i] = (wm * 128 + i * 32 + l31) * 8;
#pragma unroll
    for (int j = 0; j < 2; ++j) brows[j] = (wn * 64 + j * 32 + l31) * 8;

    // prologue: stage tile 0 -> buffer 0, full drain
#pragma unroll
    for (int j = 0; j < 4; ++j) gl_lds16(A + aoff[j], &Asm[0][ldst[j]]);
#pragma unroll
    for (int j = 0; j < 4; ++j) gl_lds16(BT + boff[j], &Bsm[0][ldst[j]]);
    asm volatile("s_waitcnt vmcnt(0)" ::: "memory");
    __builtin_amdgcn_s_barrier();

#define TILE(cur, kt)                                                           \
    {                                                                           \
        if ((kt) + 1 < NT) {                                                    \
            const int knext = ((kt) + 1) * BK;                                  \
            _Pragma("unroll")                                                   \
            for (int j = 0; j < 4; ++j)                                         \
                gl_lds16(A + aoff[j] + knext, &Asm[(cur) ^ 1][ldst[j]]);        \
            _Pragma("unroll")                                                   \
            for (int j = 0; j < 4; ++j)                                         \
                gl_lds16(BT + boff[j] + knext, &Bsm[(cur) ^ 1][ldst[j]]);       \
        }                                                                       \
        _Pragma("unroll")                                                       \
        for (int ks = 0; ks < 4; ++ks) {                                        \
            const int ch = (2 * ks + khl) ^ l7;                                 \
            int4v af[4], bf[2];                                                 \
            _Pragma("unroll")                                                   \
            for (int i = 0; i < 4; ++i)                                         \
                af[i] = *(const int4v*)&Asm[cur][(arows[i] + ch) * 16];         \
            _Pragma("unroll")                                                   \
            for (int j = 0; j < 2; ++j)                                         \
                bf[j] = *(const int4v*)&Bsm[cur][(brows[j] + ch) * 16];         \
            _Pragma("unroll")                                                   \
            for (int i = 0; i < 4; ++i) {                                       \
                _Pragma("unroll")                                               \
                for (int j = 0; j < 2; ++j)                                     \
                    acc[i][j] = __builtin_amdgcn_mfma_i32_32x32x32_i8(          \
                        af[i], bf[j], acc[i][j], 0, 0, 0);                      \
            }                                                                   \
        }                                                                       \
        asm volatile("s_waitcnt vmcnt(0)" ::: "memory");                        \
        __builtin_amdgcn_s_barrier();                                           \
    }

    for (int kt = 0; kt < NT; kt += 2) {
        TILE(0, kt)
        TILE(1, kt + 1)
    }
#undef TILE

    // epilogue: C/D layout col=lane&31, row=(reg&3)+8*(reg>>2)+4*(lane>>5)
    const int col = l31;
    const int rb = khl * 4;
#pragma unroll
    for (int j = 0; j < 2; ++j) {
        const int cn = C0 + wn * 64 + j * 32 + col;
        const float bv = __half2float(bias[cn]);
#pragma unroll
        for (int i = 0; i < 4; ++i) {
            const int rm = R0 + wm * 128 + i * 32 + rb;
#pragma unroll
            for (int reg = 0; reg < 16; ++reg) {
                const int row = rm + (reg & 3) + 8 * (reg >> 2);
                C[(size_t)row * N_DIM + cn] = (float)acc[i][j][reg] + bv;
            }
        }
    }
}

extern "C" void kernel_launch(void* const* d_in, const int* in_sizes, int n_in,
                              void* d_out, int out_size, void* d_ws, size_t ws_size,
                              hipStream_t stream) {
    const int* x = (const int*)d_in[0];
    const int* wgt = (const int*)d_in[1];
    const __half* bias = (const __half*)d_in[2];
    float* out = (float*)d_out;

    char* xp = (char*)d_ws;                                   // 32 MiB packed A
    char* wt = (char*)d_ws + (size_t)M_DIM * K_DIM;           // 4 MiB packed W^T

    pack_x_kernel<<<(M_DIM * (size_t)K_DIM) / 4 / 1024, 256, 0, stream>>>(x, xp);
    wt_pack_kernel<<<(K_DIM / 64) * (N_DIM / 64), 256, 0, stream>>>(wgt, wt);
    gemm_i8_kernel<<<(M_DIM / BM) * (N_DIM / BN), 512, 0, stream>>>(xp, wt, bias, out);
}

// Round 5
// 308.382 us; speedup vs baseline: 1.2280x; 1.0196x over previous
//
#include <hip/hip_runtime.h>
#include <hip/hip_fp16.h>

#define M_DIM 16384
#define K_DIM 2048
#define N_DIM 2048

#define BM 256
#define BN 256
#define BK 128
#define NT (K_DIM / BK)

typedef int int4v  __attribute__((ext_vector_type(4)));
typedef int int16v __attribute__((ext_vector_type(16)));

__device__ __forceinline__ void gl_lds16(const void* g, void* l) {
    __builtin_amdgcn_global_load_lds(
        (const __attribute__((address_space(1))) void*)g,
        (__attribute__((address_space(3))) void*)l,
        16, 0, 0);
}

__device__ __forceinline__ int pack4(int4v v) {
    return (v[0] & 255) | ((v[1] & 255) << 8) | ((v[2] & 255) << 16) | (v[3] << 24);
}

// x: int32 [M,K] -> int8 [M,K]; lane-contiguous loads/stores
__global__ void pack_x_kernel(const int* __restrict__ x, char* __restrict__ xp) {
    const int4v* src = (const int4v*)x;
    int* dst = (int*)xp;
    int base = blockIdx.x * 1024 + threadIdx.x;
#pragma unroll
    for (int j = 0; j < 4; ++j) {
        int i = base + j * 256;
        dst[i] = pack4(src[i]);
    }
}

// weight: int32 [K,N] -> int8 WT [N,K] (transpose + pack), 64x64 tiles via LDS
__global__ void wt_pack_kernel(const int* __restrict__ w, char* __restrict__ wt) {
    __shared__ char tile[64][68];
    int b  = blockIdx.x;
    int k0 = (b & 31) * 64;
    int n0 = (b >> 5) * 64;
    int t  = threadIdx.x;
    int r  = t >> 2;
    int c  = (t & 3) * 16;

    const int* src = w + (size_t)(k0 + r) * N_DIM + n0 + c;
    int4v a = *(const int4v*)(src + 0);
    int4v bb = *(const int4v*)(src + 4);
    int4v cc = *(const int4v*)(src + 8);
    int4v dd = *(const int4v*)(src + 12);
    *(int*)&tile[r][c + 0]  = pack4(a);
    *(int*)&tile[r][c + 4]  = pack4(bb);
    *(int*)&tile[r][c + 8]  = pack4(cc);
    *(int*)&tile[r][c + 12] = pack4(dd);
    __syncthreads();

    char buf[16];
#pragma unroll
    for (int j = 0; j < 16; ++j) buf[j] = tile[c + j][r];
    *(int4v*)(wt + (size_t)(n0 + r) * K_DIM + k0 + c) = *(int4v*)buf;
}

// GEMM: A int8 [M,K], BT int8 [N,K] -> C fp32 [M,N] (+bias)
// 256x256 tile, BK=128, 512 thr = 8 waves (2M x 4N), wave tile 128x64 =
// acc[4][2] (128 AGPRs). Double-buffered LDS 128 KiB, 1 block/CU.
// R3 diagnosis: all waves leave the tile barrier in phase, so LDS-read bursts
// (576 cyc queue) and MFMA bursts (293 cyc) ALTERNATE -> 293/869 = 34% duty,
// the measured MfmaUtil in R0/R1/R3. Fix here: register software-pipelining
// of the fragments: issue the 6 ds_read_b128 for ks+1 BEFORE the 8 MFMAs of
// ks (double-buffered frag regs, <=6 lgkm outstanding). Each wave keeps the
// LDS pipe fed while its MFMAs run -> read service and MFMA overlap instead
// of alternating. One barrier + one vmcnt(0) drain per K-tile (covered by
// ~2300 cyc of compute).
// LDS layout (16B slots, 8 chunks/row, XOR-swizzled): slot = r*8 + (cg^(r&7)).
// Staging slot-linear (gl_lds wave-uniform dest) with pre-swizzled global
// source; fragment reads give distinct slot%8 per 8-lane group.
__global__ __launch_bounds__(512, 2)
void gemm_i8_kernel(const char* __restrict__ A, const char* __restrict__ BT,
                    const __half* __restrict__ bias, float* __restrict__ C) {
    __shared__ char Asm[2][BM * BK];   // 2 x 32768 B
    __shared__ char Bsm[2][BN * BK];   // 2 x 32768 B

    const int bid = blockIdx.x;
    const int mt = bid & 63;            // m fastest: B panel (512 KB) stays hot in L2
    const int nt = bid >> 6;
    const int R0 = mt * BM, C0 = nt * BN;

    const int t = threadIdx.x;
    const int lane = t & 63;
    const int w = t >> 6;
    const int wm = w >> 2;              // 0..1 row-half (128 rows)
    const int wn = w & 3;               // 0..3 col-quarter (64 cols)
    const int l31 = lane & 31, l7 = lane & 7, khl = lane >> 5;

    int16v acc[4][2];
#pragma unroll
    for (int i = 0; i < 4; ++i)
#pragma unroll
        for (int j = 0; j < 2; ++j) acc[i][j] = (int16v)0;

    // staging: thread owns slots t + 512*j; slot s -> row s>>3, stored chunk s&7,
    // global chunk cg = (s&7)^(row&7)
    unsigned aoff[4], boff[4];
    int ldst[4];
#pragma unroll
    for (int j = 0; j < 4; ++j) {
        int s = t + j * 512;
        int r = s >> 3;
        int cg = (s & 7) ^ (r & 7);
        aoff[j] = (unsigned)(R0 + r) * K_DIM + cg * 16;
        boff[j] = (unsigned)(C0 + r) * K_DIM + cg * 16;
        ldst[j] = s * 16;
    }

    // fragment row-slot bases (row*8); row&7 == l7 (bases are mult. of 32)
    int arows[4], brows[2];
#pragma unroll
    for (int i = 0; i < 4; ++i) arows[i] = (wm * 128 + i * 32 + l31) * 8;
#pragma unroll
    for (int j = 0; j < 2; ++j) brows[j] = (wn * 64 + j * 32 + l31) * 8;

    // prologue: stage tile 0 -> buffer 0, full drain
#pragma unroll
    for (int j = 0; j < 4; ++j) gl_lds16(A + aoff[j], &Asm[0][ldst[j]]);
#pragma unroll
    for (int j = 0; j < 4; ++j) gl_lds16(BT + boff[j], &Bsm[0][ldst[j]]);
    asm volatile("s_waitcnt vmcnt(0)" ::: "memory");
    __builtin_amdgcn_s_barrier();

    // TILE: register-software-pipelined k-steps.
    //   read frags(ks=0); issue prefetch; for ks: {read frags(ks+1); MFMA(ks)}
#define TILE(cur, kt)                                                           \
    {                                                                           \
        int4v af[2][4], bf[2][2];                                               \
        {                                                                       \
            const int ch0 = (khl) ^ l7;                                         \
            _Pragma("unroll")                                                   \
            for (int i = 0; i < 4; ++i)                                         \
                af[0][i] = *(const int4v*)&Asm[cur][(arows[i] + ch0) * 16];     \
            _Pragma("unroll")                                                   \
            for (int j = 0; j < 2; ++j)                                         \
                bf[0][j] = *(const int4v*)&Bsm[cur][(brows[j] + ch0) * 16];     \
        }                                                                       \
        if ((kt) + 1 < NT) {                                                    \
            const int knext = ((kt) + 1) * BK;                                  \
            _Pragma("unroll")                                                   \
            for (int j = 0; j < 4; ++j)                                         \
                gl_lds16(A + aoff[j] + knext, &Asm[(cur) ^ 1][ldst[j]]);        \
            _Pragma("unroll")                                                   \
            for (int j = 0; j < 4; ++j)                                         \
                gl_lds16(BT + boff[j] + knext, &Bsm[(cur) ^ 1][ldst[j]]);       \
        }                                                                       \
        _Pragma("unroll")                                                       \
        for (int ks = 0; ks < 4; ++ks) {                                        \
            const int pb = ks & 1, nb = (ks & 1) ^ 1;                           \
            if (ks < 3) {                                                       \
                const int ch = (2 * (ks + 1) + khl) ^ l7;                       \
                _Pragma("unroll")                                               \
                for (int i = 0; i < 4; ++i)                                     \
                    af[nb][i] = *(const int4v*)&Asm[cur][(arows[i] + ch) * 16]; \
                _Pragma("unroll")                                               \
                for (int j = 0; j < 2; ++j)                                     \
                    bf[nb][j] = *(const int4v*)&Bsm[cur][(brows[j] + ch) * 16]; \
            }                                                                   \
            _Pragma("unroll")                                                   \
            for (int i = 0; i < 4; ++i) {                                       \
                _Pragma("unroll")                                               \
                for (int j = 0; j < 2; ++j)                                     \
                    acc[i][j] = __builtin_amdgcn_mfma_i32_32x32x32_i8(          \
                        af[pb][i], bf[pb][j], acc[i][j], 0, 0, 0);              \
            }                                                                   \
        }                                                                       \
        asm volatile("s_waitcnt vmcnt(0)" ::: "memory");                        \
        __builtin_amdgcn_s_barrier();                                           \
    }

    for (int kt = 0; kt < NT; kt += 2) {
        TILE(0, kt)
        TILE(1, kt + 1)
    }
#undef TILE

    // epilogue: C/D layout col=lane&31, row=(reg&3)+8*(reg>>2)+4*(lane>>5)
    const int col = l31;
    const int rb = khl * 4;
#pragma unroll
    for (int j = 0; j < 2; ++j) {
        const int cn = C0 + wn * 64 + j * 32 + col;
        const float bv = __half2float(bias[cn]);
#pragma unroll
        for (int i = 0; i < 4; ++i) {
            const int rm = R0 + wm * 128 + i * 32 + rb;
#pragma unroll
            for (int reg = 0; reg < 16; ++reg) {
                const int row = rm + (reg & 3) + 8 * (reg >> 2);
                C[(size_t)row * N_DIM + cn] = (float)acc[i][j][reg] + bv;
            }
        }
    }
}

extern "C" void kernel_launch(void* const* d_in, const int* in_sizes, int n_in,
                              void* d_out, int out_size, void* d_ws, size_t ws_size,
                              hipStream_t stream) {
    const int* x = (const int*)d_in[0];
    const int* wgt = (const int*)d_in[1];
    const __half* bias = (const __half*)d_in[2];
    float* out = (float*)d_out;

    char* xp = (char*)d_ws;                                   // 32 MiB packed A
    char* wt = (char*)d_ws + (size_t)M_DIM * K_DIM;           // 4 MiB packed W^T

    pack_x_kernel<<<(M_DIM * (size_t)K_DIM) / 4 / 1024, 256, 0, stream>>>(x, xp);
    wt_pack_kernel<<<(K_DIM / 64) * (N_DIM / 64), 256, 0, stream>>>(wgt, wt);
    gemm_i8_kernel<<<(M_DIM / BM) * (N_DIM / BN), 512, 0, stream>>>(xp, wt, bias, out);
}